// Round 1
// baseline (2319.123 us; speedup 1.0000x reference)
//
#include <hip/hip_runtime.h>

#define KCODES 1024
#define DDIM 128
#define HW 64
#define BATCH 32
#define NPIX (BATCH * HW * HW)      // 131072 pixels
#define PLANE (HW * HW)             // 4096
#define BSTRIDE (DDIM * PLANE)      // 524288 floats per batch image
#define MARGIN 1e-4f

// ---------------------------------------------------------------------------
// prep: Bsum[k] = numpy-pairwise sum of codebook[k,:]^2  (fp32, no contraction,
// exact numpy pairwise order for n=128: 8 accumulators, tree combine)
// ---------------------------------------------------------------------------
__global__ __launch_bounds__(256) void prep_kernel(const float* __restrict__ cb,
                                                   float* __restrict__ Bsum) {
#pragma clang fp contract(off)
    int k = blockIdx.x * blockDim.x + threadIdx.x;
    if (k >= KCODES) return;
    const float* row = cb + k * DDIM;
    float r[8];
#pragma unroll
    for (int j = 0; j < 8; ++j) { float x = row[j]; r[j] = x * x; }
#pragma unroll
    for (int i = 8; i < DDIM; i += 8) {
#pragma unroll
        for (int j = 0; j < 8; ++j) { float x = row[i + j]; r[j] = r[j] + x * x; }
    }
    Bsum[k] = ((r[0] + r[1]) + (r[2] + r[3])) + ((r[4] + r[5]) + (r[6] + r[7]));
}

// ---------------------------------------------------------------------------
// phase 1: one wave per (b,h), lane = w. z-row (128 fp32) cached in VGPRs.
// Distances s_k = B_k - 2*dot (fp32, 4 accumulators). Track min1/min2.
// Unambiguous -> write codebook row. Ambiguous -> append to list.
// ---------------------------------------------------------------------------
__global__ __launch_bounds__(256) void phase1_kernel(
    const float* __restrict__ z, const float* __restrict__ cb,
    const float* __restrict__ Bsum, float* __restrict__ out,
    int* __restrict__ cnt, int* __restrict__ list) {
    int gid = blockIdx.x * blockDim.x + threadIdx.x;
    int wave = gid >> 6;            // 0..2047 = (b,h)
    int lane = gid & 63;            // w
    int b = wave >> 6, h = wave & 63;

    const float* zp = z + (size_t)b * BSTRIDE + h * HW + lane;
    float zr[DDIM];
#pragma unroll
    for (int i = 0; i < DDIM; ++i) zr[i] = zp[(size_t)i * PLANE];

    float min1 = 3.4e38f, min2 = 3.4e38f;
    int idx1 = 0;
    for (int k = 0; k < KCODES; ++k) {
        const float* c = cb + k * DDIM;   // uniform address -> scalar loads
        float a0 = 0.f, a1 = 0.f, a2 = 0.f, a3 = 0.f;
#pragma unroll
        for (int i = 0; i < DDIM; i += 4) {
            a0 = __builtin_fmaf(zr[i + 0], c[i + 0], a0);
            a1 = __builtin_fmaf(zr[i + 1], c[i + 1], a1);
            a2 = __builtin_fmaf(zr[i + 2], c[i + 2], a2);
            a3 = __builtin_fmaf(zr[i + 3], c[i + 3], a3);
        }
        float dot = (a0 + a1) + (a2 + a3);
        float dist = Bsum[k] - 2.0f * dot;
        if (dist < min1) { min2 = min1; min1 = dist; idx1 = k; }
        else if (dist < min2) { min2 = dist; }
    }

    // write best guess for every pixel (phase 3 overwrites ambiguous ones)
    float* op = out + (size_t)b * BSTRIDE + h * HW + lane;
    const float* cw = cb + idx1 * DDIM;
#pragma unroll 8
    for (int i = 0; i < DDIM; ++i) op[(size_t)i * PLANE] = cw[i];

    if (min2 - min1 <= MARGIN) {
        int pos = atomicAdd(cnt, 1);
        list[pos] = wave * 64 + lane;   // pixel id in (b,h,w) order
    }
}

// ---------------------------------------------------------------------------
// phase 3: one wave per ambiguous pixel (grid-stride). Lane handles 16 codes.
// Recompute s_k, wave-min, then for candidates within MARGIN emulate numpy's
// fp32 distance bit-for-bit:
//   A   = numpy-pairwise sum of z^2 (fp32, no FMA contraction)
//   p   = dot in fp64 (proxy for BLAS fp32 accumulation, error ~1e-9)
//   D_k = fl32( fl32(A + B_k) - fl32(2*p) )
// winner = lexicographic min (D_k, k)  == numpy first-index argmin.
// ---------------------------------------------------------------------------
__global__ __launch_bounds__(256) void phase3_kernel(
    const float* __restrict__ z, const float* __restrict__ cb,
    const float* __restrict__ Bsum, float* __restrict__ out,
    const int* __restrict__ cnt, const int* __restrict__ list) {
    int gid = blockIdx.x * blockDim.x + threadIdx.x;
    int gwave = gid >> 6;
    int lane = gid & 63;
    int nwaves = (gridDim.x * blockDim.x) >> 6;
    int n = *cnt;

    for (int item = gwave; item < n; item += nwaves) {
        int pix = list[item];
        int b = pix >> 12, h = (pix >> 6) & 63, w = pix & 63;
        const float* zp = z + (size_t)b * BSTRIDE + h * HW + w;
        float zr[DDIM];
#pragma unroll
        for (int i = 0; i < DDIM; ++i) zr[i] = zp[(size_t)i * PLANE];

        // pass A: fp32 distances for this lane's 16 codes
        float s[16];
        float smin = 3.4e38f;
#pragma unroll
        for (int j = 0; j < 16; ++j) {
            int k = lane * 16 + j;
            const float* c = cb + k * DDIM;
            float a0 = 0.f, a1 = 0.f, a2 = 0.f, a3 = 0.f;
#pragma unroll
            for (int i = 0; i < DDIM; i += 4) {
                a0 = __builtin_fmaf(zr[i + 0], c[i + 0], a0);
                a1 = __builtin_fmaf(zr[i + 1], c[i + 1], a1);
                a2 = __builtin_fmaf(zr[i + 2], c[i + 2], a2);
                a3 = __builtin_fmaf(zr[i + 3], c[i + 3], a3);
            }
            float dot = (a0 + a1) + (a2 + a3);
            s[j] = Bsum[k] - 2.0f * dot;
            smin = fminf(smin, s[j]);
        }
        for (int off = 32; off > 0; off >>= 1)
            smin = fminf(smin, __shfl_xor(smin, off, 64));

        // A: numpy pairwise of z^2 (no contraction!)
        float Apair;
        {
#pragma clang fp contract(off)
            float r[8];
#pragma unroll
            for (int j = 0; j < 8; ++j) { float x = zr[j]; r[j] = x * x; }
#pragma unroll
            for (int i = 8; i < DDIM; i += 8) {
#pragma unroll
                for (int j = 0; j < 8; ++j) { float x = zr[i + j]; r[j] = r[j] + x * x; }
            }
            Apair = ((r[0] + r[1]) + (r[2] + r[3])) + ((r[4] + r[5]) + (r[6] + r[7]));
        }

        // pass B: emulate numpy fp32 D for candidates
        float bd = 3.4e38f; int bk = KCODES;
#pragma unroll
        for (int j = 0; j < 16; ++j) {
            if (s[j] <= smin + MARGIN) {
                int k = lane * 16 + j;
                const float* c = cb + k * DDIM;
                double acc = 0.0;
#pragma unroll
                for (int i = 0; i < DDIM; ++i)
                    acc = fma((double)zr[i], (double)c[i], acc);
                float u = (float)(2.0 * acc);
                float t, Dk;
                {
#pragma clang fp contract(off)
                    t = Apair + Bsum[k];
                    Dk = t - u;
                }
                if (Dk < bd || (Dk == bd && k < bk)) { bd = Dk; bk = k; }
            }
        }

        // lexicographic wave reduction (min D, then min k)
        for (int off = 32; off > 0; off >>= 1) {
            float od = __shfl_xor(bd, off, 64);
            int   ok = __shfl_xor(bk, off, 64);
            if (od < bd || (od == bd && ok < bk)) { bd = od; bk = ok; }
        }

        float* op = out + (size_t)b * BSTRIDE + h * HW + w;
        const float* cw = cb + bk * DDIM;
        for (int ci = lane; ci < DDIM; ci += 64)
            op[(size_t)ci * PLANE] = cw[ci];
    }
}

// ---------------------------------------------------------------------------
extern "C" void kernel_launch(void* const* d_in, const int* in_sizes, int n_in,
                              void* d_out, int out_size, void* d_ws, size_t ws_size,
                              hipStream_t stream) {
    const float* z  = (const float*)d_in[0];
    const float* cb = (const float*)d_in[1];
    float* out = (float*)d_out;

    // workspace layout: Bsum[1024] | pad | cnt | list[NPIX]
    float* Bsum = (float*)d_ws;
    int* cnt  = (int*)((char*)d_ws + 4096);
    int* list = (int*)((char*)d_ws + 4096 + 256);

    hipMemsetAsync(cnt, 0, sizeof(int), stream);   // ws is re-poisoned each call
    prep_kernel<<<KCODES / 256, 256, 0, stream>>>(cb, Bsum);
    phase1_kernel<<<NPIX / 256, 256, 0, stream>>>(z, cb, Bsum, out, cnt, list);
    phase3_kernel<<<512, 256, 0, stream>>>(z, cb, Bsum, out, cnt, list);
}